// Round 7
// baseline (254493.628 us; speedup 1.0000x reference)
//
#include <hip/hip_runtime.h>
#include <math.h>

#define NWG    256
#define TPB    1024        // 16 waves
#define H      1536
#define S_TOT  2048
#define RPW    6           // h rows owned per WG
#define GRW    24          // gate rows per WG (4 gates x 6 rows)
#define OUTP   2048        // probs offset in d_out
#define W3ROWS 23          // W_ih1 rows in LDS (row 23 streamed from global)

#define SMEM_BYTES (W3ROWS * H * 4)   // 141312 B dynamic LDS

// Per-wave register weights: 3 rows x 24 floats as 18 named F4 structs.
// Rounds 1-6: 192 resident floats vs a 128-VGPR budget made LLVM sink the
// weight loads into the loop (FETCH invariant across array/vector/struct
// spellings). Fix is demand-side: 16 waves -> 3 rows/wave = 72 floats.
struct F4 { float x, y, z, w; };

struct Params {
  const float* inputs; const float* h_init; const float* c_init;
  const float* W_ih0; const float* W_hh0; const float* b_ih0; const float* b_hh0;
  const float* W_ih1; const float* W_hh1; const float* b_ih1; const float* b_hh1;
  const float* W_lin; const float* b_lin; const float* lookup;
  float* out; float* h0g; float* h1g; unsigned* bar;
};

__device__ __forceinline__ float gload(const float* p) {
  return __hip_atomic_load(p, __ATOMIC_RELAXED, __HIP_MEMORY_SCOPE_AGENT);
}
__device__ __forceinline__ void gstore(float* p, float v) {
  __hip_atomic_store(p, v, __ATOMIC_RELAXED, __HIP_MEMORY_SCOPE_AGENT);
}

// JAX threefry2x32 (20 rounds), bit-exact.
__device__ __forceinline__ void tf2x32(unsigned k0, unsigned k1,
                                       unsigned x0, unsigned x1,
                                       unsigned& o0, unsigned& o1) {
  unsigned ks2 = k0 ^ k1 ^ 0x1BD11BDAu;
  x0 += k0; x1 += k1;
#define TFR(r) { x0 += x1; x1 = ((x1 << r) | (x1 >> (32 - r))); x1 ^= x0; }
  TFR(13) TFR(15) TFR(26) TFR(6)   x0 += k1;  x1 += ks2 + 1u;
  TFR(17) TFR(29) TFR(16) TFR(24)  x0 += ks2; x1 += k0 + 2u;
  TFR(13) TFR(15) TFR(26) TFR(6)   x0 += k0;  x1 += k1 + 3u;
  TFR(17) TFR(29) TFR(16) TFR(24)  x0 += k1;  x1 += ks2 + 4u;
  TFR(13) TFR(15) TFR(26) TFR(6)   x0 += ks2; x1 += k0 + 5u;
#undef TFR
  o0 = x0; o1 = x1;
}

__device__ __forceinline__ double bsum64(double v) {
#pragma unroll
  for (int o = 32; o > 0; o >>= 1) v += __shfl_xor(v, o);
  return v;
}

__device__ __forceinline__ float sigf(float x) { return 1.0f / (1.0f + expf(-x)); }

// All-to-all flag barrier. Publisher: release fence + release store. Pollers:
// wave 0 only, RELAXED loads in the spin loop, one agent acquire fence at
// exit. Monotone >= compare (sign bit of OR of deltas): safe vs 0xAA poison
// and vs fast WGs already publishing epoch e+1.
__device__ __forceinline__ void flagbar(unsigned* bar, unsigned e, int tid, int wg) {
  __builtin_amdgcn_fence(__ATOMIC_RELEASE, "agent");
  __syncthreads();      // everyone's data published before flag
  if (tid == 0)
    __hip_atomic_store(&bar[wg], e, __ATOMIC_RELEASE, __HIP_MEMORY_SCOPE_AGENT);
  if (tid < 64) {
    const unsigned* f = bar + tid * 4;
    bool done;
    do {
      int d0 = (int)(__hip_atomic_load(f + 0, __ATOMIC_RELAXED, __HIP_MEMORY_SCOPE_AGENT) - e);
      int d1 = (int)(__hip_atomic_load(f + 1, __ATOMIC_RELAXED, __HIP_MEMORY_SCOPE_AGENT) - e);
      int d2 = (int)(__hip_atomic_load(f + 2, __ATOMIC_RELAXED, __HIP_MEMORY_SCOPE_AGENT) - e);
      int d3 = (int)(__hip_atomic_load(f + 3, __ATOMIC_RELAXED, __HIP_MEMORY_SCOPE_AGENT) - e);
      done = ((d0 | d1 | d2 | d3) >= 0);   // all >= 0
    } while (!__all(done));
    __builtin_amdgcn_fence(__ATOMIC_ACQUIRE, "agent");
  }
  __syncthreads();
}

__global__
__attribute__((amdgpu_flat_work_group_size(TPB, TPB), amdgpu_waves_per_eu(4, 4)))
void lstm_persistent(Params P) {
  const int tid  = threadIdx.x;
  const int wg   = blockIdx.x;
  const int wv   = tid >> 6;     // 0..15
  const int lane = tid & 63;

  extern __shared__ float smem[];
  float* s_W3 = smem;            // W3ROWS x H : W_ih1 per-WG rows 0..22, [r*H + col]

  __shared__ float s_Wih0[GRW * 32];
  __shared__ float s_h0[H], s_h1[H];
  __shared__ float s_bih0[GRW], s_bhh0[GRW], s_bih1[GRW], s_bhh1[GRW];
  __shared__ float s_hh1dot[GRW], s_gate[GRW];
  __shared__ float s_x[32];
  __shared__ float s_c0[RPW], s_c1[RPW];
  __shared__ float s_logits[16];
  __shared__ float s_blin[10], s_lookup[10];
  __shared__ int   s_action;

  // ---------------- init ----------------
  for (int k = tid; k < GRW * 32; k += TPB) {
    int idx = k >> 5, kk = k & 31;
    int q = idx / RPW, u = idx % RPW;
    int gr = q * H + wg * RPW + u;
    s_Wih0[k] = P.W_ih0[gr * 32 + kk];
  }
  for (int k = tid; k < W3ROWS * H; k += TPB) {
    int r = k / H, col = k % H;
    int gr = (r / RPW) * H + wg * RPW + (r % RPW);
    s_W3[k] = P.W_ih1[(size_t)gr * H + col];
  }
  if (tid < GRW) {
    int q = tid / RPW, u = tid % RPW;
    int gr = q * H + wg * RPW + u;
    s_bih0[tid] = P.b_ih0[gr]; s_bhh0[tid] = P.b_hh0[gr];
    s_bih1[tid] = P.b_ih1[gr]; s_bhh1[tid] = P.b_hh1[gr];
  }
  if (tid < 10) { s_blin[tid] = P.b_lin[tid]; s_lookup[tid] = P.lookup[tid]; }
  if (tid < RPW) {
    s_c0[tid] = P.c_init[wg * RPW + tid];
    s_c1[tid] = P.c_init[H + wg * RPW + tid];
    gstore(P.h0g + wg * RPW + tid, P.h_init[wg * RPW + tid]);
    gstore(P.h1g + wg * RPW + tid, P.h_init[H + wg * RPW + tid]);
  }

  // Role-based register rows: waves 0..7 -> W_hh0 rows 3wv..3wv+2 (layer-0
  // recurrent); waves 8..15 -> W_hh1 rows 3(wv-8)..3(wv-8)+2 (layer-1
  // recurrent). Element t of a row lives at col lane + t*64.
#define ROWP(M, IDX) ((M) + (size_t)((((IDX) / RPW) * H) + wg * RPW + ((IDX) % RPW)) * H)
  const int abase = (wv < 8) ? (wv * 3) : ((wv - 8) * 3);
  const float* Wbig = (wv < 8) ? P.W_hh0 : P.W_hh1;
  const float* q0 = ROWP(Wbig, abase + 0);
  const float* q1 = ROWP(Wbig, abase + 1);
  const float* q2 = ROWP(Wbig, abase + 2);
  const float* pW23 = ROWP(P.W_ih1, 23);                 // wave 7, phase 2 (L2-hot)
  const float* pLin = P.W_lin + (size_t)((wv < 10) ? wv : 0) * H;  // logits row (L2-hot)
#undef ROWP
#define MK4(p, g) F4{ (p)[lane + ((4*(g)+0) << 6)], (p)[lane + ((4*(g)+1) << 6)], \
                      (p)[lane + ((4*(g)+2) << 6)], (p)[lane + ((4*(g)+3) << 6)] }
  F4 r0_0 = MK4(q0,0), r0_1 = MK4(q0,1), r0_2 = MK4(q0,2),
     r0_3 = MK4(q0,3), r0_4 = MK4(q0,4), r0_5 = MK4(q0,5);
  F4 r1_0 = MK4(q1,0), r1_1 = MK4(q1,1), r1_2 = MK4(q1,2),
     r1_3 = MK4(q1,3), r1_4 = MK4(q1,4), r1_5 = MK4(q1,5);
  F4 r2_0 = MK4(q2,0), r2_1 = MK4(q2,1), r2_2 = MK4(q2,2),
     r2_3 = MK4(q2,3), r2_4 = MK4(q2,4), r2_5 = MK4(q2,5);
#undef MK4

  unsigned ep = 1;
  flagbar(P.bar, ep++, tid, wg);

  // ---------------- main sequential loop ----------------
  for (int s = 0; s <= S_TOT; ++s) {
    // stage h0prev / h1prev
    for (int k = tid; k < H; k += TPB) {
      s_h0[k] = gload(P.h0g + k);
      s_h1[k] = gload(P.h1g + k);
    }
    __syncthreads();

    if (s > 0) {
      int sp = s - 1;
      // logits = h1prev @ W_lin.T + b_lin (redundant per WG; waves 0..9, one
      // row each; W_lin via gload each step — 60 KB shared, L2-hot, and
      // atomic loads are never hoisted into long-lived registers).
      if (wv < 10) {
        double acc = 0.0;
#pragma unroll
        for (int t = 0; t < 24; ++t) {
          const int off = lane + (t << 6);
          acc += (double)gload(pLin + off) * (double)s_h1[off];
        }
        acc = bsum64(acc);
        if (lane == 0) s_logits[wv] = __fadd_rn((float)acc, s_blin[wv]);
      }
      __syncthreads();

      if (wv == 0) {
        // key_sp = threefry(key(42)=(0,42); 0, sp)   [partitionable split]
        unsigned kk0, kk1; tf2x32(0u, 42u, 0u, (unsigned)sp, kk0, kk1);
        unsigned b1, b2; tf2x32(kk0, kk1, 0u, (unsigned)lane, b1, b2);
        unsigned bits = b1 ^ b2;
        float uraw = __fsub_rn(__uint_as_float((bits >> 9) | 0x3F800000u), 1.0f);
        const float TINY = 1.17549435e-38f;
        float u  = fmaxf(TINY, __fadd_rn(uraw, TINY));
        float gum = -logf(-logf(u));
        float lg = (lane < 10) ? s_logits[lane] : 0.0f;
        float y  = (lane < 10) ? __fadd_rn(lg, gum) : -INFINITY;
        int ai = lane;
#pragma unroll
        for (int o = 1; o < 16; o <<= 1) {
          float oy = __shfl_xor(y, o); int oi = __shfl_xor(ai, o);
          if (oy > y || (oy == y && oi < ai)) { y = oy; ai = oi; }
        }
        float lm = (lane < 10) ? lg : -INFINITY;
#pragma unroll
        for (int o = 1; o < 16; o <<= 1) lm = fmaxf(lm, __shfl_xor(lm, o));
        float e2 = (lane < 10) ? expf(__fsub_rn(lg, lm)) : 0.0f;
        float ssum = e2;
#pragma unroll
        for (int o = 1; o < 16; o <<= 1) ssum = __fadd_rn(ssum, __shfl_xor(ssum, o));
        if (lane == 0) s_action = ai;
        if (wg == 0) {
          if (lane < 10) P.out[OUTP + sp * 10 + lane] = e2 / ssum;
          if (lane == 0) P.out[sp] = (float)ai;
        }
      }
      __syncthreads();
      if (tid == 0) {
        int jp = sp & 31;
        if (jp != 0) s_x[jp] = __fmul_rn(s_x[jp], s_lookup[s_action]);
      }
      __syncthreads();
    }

    if (s == S_TOT) break;
    int ii = s >> 5, jj = s & 31;
    if (jj == 0 && tid < 32) s_x[tid] = P.inputs[ii * 32 + tid];
    __syncthreads();

    // ---------- phase 1: waves 0..7 gates0 (W_ih0·x + W_hh0·h0prev);
    //            waves 8..15 W_hh1·h1prev -> s_hh1dot ----------
    {
      const float* hsrc = (wv < 8) ? s_h0 : s_h1;
      double a0 = 0, a1 = 0, a2 = 0;
      // per-accumulator add order: t ascending 0..23 (groups of 4) — exact
      // fp64 chain of rounds 3-6 (bit-exact verified).
#define GRPH(g) { \
      const int off = lane + ((g) << 8); \
      const double hv0 = (double)hsrc[off],       hv1 = (double)hsrc[off + 64], \
                   hv2 = (double)hsrc[off + 128], hv3 = (double)hsrc[off + 192]; \
      a0 += (double)r0_##g.x * hv0; a0 += (double)r0_##g.y * hv1; a0 += (double)r0_##g.z * hv2; a0 += (double)r0_##g.w * hv3; \
      a1 += (double)r1_##g.x * hv0; a1 += (double)r1_##g.y * hv1; a1 += (double)r1_##g.z * hv2; a1 += (double)r1_##g.w * hv3; \
      a2 += (double)r2_##g.x * hv0; a2 += (double)r2_##g.y * hv1; a2 += (double)r2_##g.z * hv2; a2 += (double)r2_##g.w * hv3; \
      }
      GRPH(0) GRPH(1) GRPH(2) GRPH(3) GRPH(4) GRPH(5)
#undef GRPH
      a0 = bsum64(a0); a1 = bsum64(a1); a2 = bsum64(a2);
      if (wv < 8) {
        double xa0, xa1, xa2;
#define XDOT(slot, dst) { \
        double pp = (lane < 32) \
          ? (double)s_Wih0[(((wv * 3 + (slot)) << 5) + lane)] * (double)s_x[lane] : 0.0; \
        pp += __shfl_xor(pp, 16); pp += __shfl_xor(pp, 8); pp += __shfl_xor(pp, 4); \
        pp += __shfl_xor(pp, 2);  pp += __shfl_xor(pp, 1); \
        dst = pp; }
        XDOT(0, xa0) XDOT(1, xa1) XDOT(2, xa2)
#undef XDOT
        if (lane == 0) {
#define WB1(slot, xav, aav) { \
          const int idx = wv * 3 + (slot); \
          s_gate[idx] = __fadd_rn(__fadd_rn(__fadd_rn((float)(xav), s_bih0[idx]), \
                                            (float)(aav)), s_bhh0[idx]); }
          WB1(0, xa0, a0) WB1(1, xa1, a1) WB1(2, xa2, a2)
#undef WB1
        }
      } else {
        if (lane == 0) {
          const int idx = (wv - 8) * 3;
          s_hh1dot[idx]     = (float)a0;
          s_hh1dot[idx + 1] = (float)a1;
          s_hh1dot[idx + 2] = (float)a2;
        }
      }
    }
    __syncthreads();
    if (tid < RPW) {
      int u = tid;
      float gi = s_gate[u], gf = s_gate[6 + u], gg = s_gate[12 + u], go = s_gate[18 + u];
      float c = __fadd_rn(__fmul_rn(sigf(gf), s_c0[u]), __fmul_rn(sigf(gi), tanhf(gg)));
      s_c0[u] = c;
      float h = __fmul_rn(sigf(go), tanhf(c));
      gstore(P.h0g + wg * RPW + u, h);
    }
    flagbar(P.bar, ep++, tid, wg);

    // ---------- phase 2: gates1 = W_ih1·h0 + (stashed W_hh1·h1prev) ----------
    for (int k = tid; k < H; k += TPB) s_h0[k] = gload(P.h0g + k);
    __syncthreads();
    if (wv < 7) {
      const int rb0 = (wv * 3) * H, rb1 = rb0 + H, rb2 = rb1 + H;
      double a0 = 0, a1 = 0, a2 = 0;
#define GRPL(g) { \
      const int off = lane + ((g) << 8); \
      const double hv0 = (double)s_h0[off],       hv1 = (double)s_h0[off + 64], \
                   hv2 = (double)s_h0[off + 128], hv3 = (double)s_h0[off + 192]; \
      a0 += (double)s_W3[rb0 + off] * hv0;       a0 += (double)s_W3[rb0 + off + 64] * hv1; \
      a0 += (double)s_W3[rb0 + off + 128] * hv2; a0 += (double)s_W3[rb0 + off + 192] * hv3; \
      a1 += (double)s_W3[rb1 + off] * hv0;       a1 += (double)s_W3[rb1 + off + 64] * hv1; \
      a1 += (double)s_W3[rb1 + off + 128] * hv2; a1 += (double)s_W3[rb1 + off + 192] * hv3; \
      a2 += (double)s_W3[rb2 + off] * hv0;       a2 += (double)s_W3[rb2 + off + 64] * hv1; \
      a2 += (double)s_W3[rb2 + off + 128] * hv2; a2 += (double)s_W3[rb2 + off + 192] * hv3; \
      }
      GRPL(0) GRPL(1) GRPL(2) GRPL(3) GRPL(4) GRPL(5)
#undef GRPL
      a0 = bsum64(a0); a1 = bsum64(a1); a2 = bsum64(a2);
      if (lane == 0) {
#define WB2(slot, aav) { \
        const int idx = wv * 3 + (slot); \
        s_gate[idx] = __fadd_rn(__fadd_rn(__fadd_rn((float)(aav), s_bih1[idx]), \
                                          s_hh1dot[idx]), s_bhh1[idx]); }
        WB2(0, a0) WB2(1, a1) WB2(2, a2)
#undef WB2
      }
    } else if (wv == 7) {
      const int rb0 = 21 * H, rb1 = 22 * H;
      double a0 = 0, a1 = 0, a2 = 0;    // rows 21,22 from LDS; row 23 from global (L2-hot)
#define GRPE(g) { \
      const int off = lane + ((g) << 8); \
      const double hv0 = (double)s_h0[off],       hv1 = (double)s_h0[off + 64], \
                   hv2 = (double)s_h0[off + 128], hv3 = (double)s_h0[off + 192]; \
      a0 += (double)s_W3[rb0 + off] * hv0;       a0 += (double)s_W3[rb0 + off + 64] * hv1; \
      a0 += (double)s_W3[rb0 + off + 128] * hv2; a0 += (double)s_W3[rb0 + off + 192] * hv3; \
      a1 += (double)s_W3[rb1 + off] * hv0;       a1 += (double)s_W3[rb1 + off + 64] * hv1; \
      a1 += (double)s_W3[rb1 + off + 128] * hv2; a1 += (double)s_W3[rb1 + off + 192] * hv3; \
      a2 += (double)gload(pW23 + off) * hv0;       a2 += (double)gload(pW23 + off + 64) * hv1; \
      a2 += (double)gload(pW23 + off + 128) * hv2; a2 += (double)gload(pW23 + off + 192) * hv3; \
      }
      GRPE(0) GRPE(1) GRPE(2) GRPE(3) GRPE(4) GRPE(5)
#undef GRPE
      a0 = bsum64(a0); a1 = bsum64(a1); a2 = bsum64(a2);
      if (lane == 0) {
#define WB2E(idx, aav) { \
        s_gate[idx] = __fadd_rn(__fadd_rn(__fadd_rn((float)(aav), s_bih1[idx]), \
                                          s_hh1dot[idx]), s_bhh1[idx]); }
        WB2E(21, a0) WB2E(22, a1) WB2E(23, a2)
#undef WB2E
      }
    }
    __syncthreads();
    if (tid < RPW) {
      int u = tid;
      float gi = s_gate[u], gf = s_gate[6 + u], gg = s_gate[12 + u], go = s_gate[18 + u];
      float c = __fadd_rn(__fmul_rn(sigf(gf), s_c1[u]), __fmul_rn(sigf(gi), tanhf(gg)));
      s_c1[u] = c;
      float h = __fmul_rn(sigf(go), tanhf(c));
      gstore(P.h1g + wg * RPW + u, h);
    }
    flagbar(P.bar, ep++, tid, wg);
  }
}

extern "C" void kernel_launch(void* const* d_in, const int* in_sizes, int n_in,
                              void* d_out, int out_size, void* d_ws, size_t ws_size,
                              hipStream_t stream) {
  (void)in_sizes; (void)n_in; (void)out_size; (void)ws_size;
  Params p;
  p.inputs = (const float*)d_in[0];
  p.h_init = (const float*)d_in[1];
  p.c_init = (const float*)d_in[2];
  p.W_ih0  = (const float*)d_in[3];
  p.W_hh0  = (const float*)d_in[4];
  p.b_ih0  = (const float*)d_in[5];
  p.b_hh0  = (const float*)d_in[6];
  p.W_ih1  = (const float*)d_in[7];
  p.W_hh1  = (const float*)d_in[8];
  p.b_ih1  = (const float*)d_in[9];
  p.b_hh1  = (const float*)d_in[10];
  p.W_lin  = (const float*)d_in[11];
  p.b_lin  = (const float*)d_in[12];
  p.lookup = (const float*)d_in[13];
  p.out    = (float*)d_out;
  float* ws = (float*)d_ws;
  p.h0g = ws;
  p.h1g = ws + H;
  p.bar = (unsigned*)(ws + 2 * H);

  // opt-in for >64 KB dynamic LDS (idempotent; host-side, graph-capture safe)
  hipFuncSetAttribute((const void*)lstm_persistent,
                      hipFuncAttributeMaxDynamicSharedMemorySize, SMEM_BYTES);
  hipLaunchKernelGGL(lstm_persistent, dim3(NWG), dim3(TPB), SMEM_BYTES, stream, p);
}